// Round 9
// baseline (550.589 us; speedup 1.0000x reference)
//
#include <hip/hip_runtime.h>

#define B 8
#define N 100000
#define NE 3200000
#define CHUNK2_LOG 7
#define CHUNK2 128            // nodes per record bucket
#define NCHUNK2 782           // ceil(N / 128)
#define CAP2 9216             // per-bucket record capacity (mean 8192, +11 sigma)
#define EPB 1024              // records_kernel edges per block
#define RPB (2 * EPB)         // records staged per block = 2048
#define SCANW 1024            // scan width (pow2 >= NCHUNK2)

typedef float f32x4 __attribute__((ext_vector_type(4)));
typedef unsigned u32x2 __attribute__((ext_vector_type(2)));

// Thin 8-B records: key = (me_local<<17)|other, val = conductance bits.
// Contribution to node me is ALWAYS +c*(h[me]-h[other]) for both endpoints.
// ROUND-9: phase1 split into flows_kernel (pure streaming, no LDS — runs at
// VMEM bottleneck) and records_kernel (pure binning, no gathers — runs at LDS
// bottleneck). Fused they were ADDITIVE, not overlapped (25.6 cy/edge ~=
// 16 atomic + 6 VMEM + 4 VALU, r8 counters). Sortgather widened to 512 thr
// (occupancy 8 -> 16 waves/CU at the same 2 blocks/CU LDS limit).
__device__ u32x2 g_rec2[(size_t)NCHUNK2 * CAP2];                 // 57.7 MB
__device__ int   g_cursor2[NCHUNK2];
__device__ float g_heads_t[N * B];                               // node-major heads
__device__ float g_accum;

// ---------------------------------------------------------------------------
__global__ __launch_bounds__(256) void zero_kernel() {
    for (int i = threadIdx.x; i < NCHUNK2; i += 256) g_cursor2[i] = 0;
    if (threadIdx.x == 0) g_accum = 0.0f;
}

// heads (B,N) -> heads_t (N,B): each node's 8 batch values contiguous (32 B).
__global__ __launch_bounds__(256) void transpose_kernel(
    const float* __restrict__ node_heads)
{
    int i = blockIdx.x * blockDim.x + threadIdx.x;   // i = n*8 + b
    if (i >= N * B) return;
    int n = i >> 3, b = i & 7;
    g_heads_t[i] = node_heads[b * N + n];            // stays L2/L3-hot for gathers
}

// ---------------------------------------------------------------------------
// Flows: pure streaming+gather, zero LDS -> high occupancy, VMEM-bound.
// ---------------------------------------------------------------------------
__global__ __launch_bounds__(256) void flows_kernel(
    const int* __restrict__ edge_index,     // (2, E) int32
    const float* __restrict__ edge_attr,    // (E, 2)
    float* __restrict__ flows_out)          // (B, E)
{
    int e = blockIdx.x * blockDim.x + threadIdx.x;
    if (e >= NE) return;
    int s = edge_index[e];
    int d = edge_index[NE + e];
    float c = edge_attr[2 * (size_t)e];

    const f32x4* hs4 = (const f32x4*)&g_heads_t[s << 3];
    const f32x4* hd4 = (const f32x4*)&g_heads_t[d << 3];
    f32x4 a0 = hs4[0], a1 = hs4[1];
    f32x4 b0 = hd4[0], b1 = hd4[1];
    f32x4 f0 = c * (a0 - b0);
    f32x4 f1 = c * (a1 - b1);

    __builtin_nontemporal_store(f0.x, &flows_out[0 * NE + e]);
    __builtin_nontemporal_store(f0.y, &flows_out[1 * NE + e]);
    __builtin_nontemporal_store(f0.z, &flows_out[2 * NE + e]);
    __builtin_nontemporal_store(f0.w, &flows_out[3 * NE + e]);
    __builtin_nontemporal_store(f1.x, &flows_out[4 * NE + e]);
    __builtin_nontemporal_store(f1.y, &flows_out[5 * NE + e]);
    __builtin_nontemporal_store(f1.z, &flows_out[6 * NE + e]);
    __builtin_nontemporal_store(f1.w, &flows_out[7 * NE + e]);
}

// ---------------------------------------------------------------------------
// Records: bin edge endpoints by 128-node chunk. No gathers, no flow stores —
// the LDS counting-sort runs without VMEM-latency interference.
// LDS ~33 KB -> 4 blocks/CU (16 waves).
// ---------------------------------------------------------------------------
__global__ __launch_bounds__(256) void records_kernel(
    const int* __restrict__ edge_index,     // (2, E) int32
    const float* __restrict__ edge_attr)    // (E, 2)
{
    __shared__ int   hist[NCHUNK2];
    __shared__ int   lbase[NCHUNK2];
    __shared__ int   gbase[NCHUNK2];
    __shared__ int   lcur[NCHUNK2];
    __shared__ int   scanbuf[SCANW];
    __shared__ u32x2 s_rec[RPB];        // 16 KB staging

    int tid = threadIdx.x;
    int e0 = blockIdx.x * EPB;

    for (int i = tid; i < NCHUNK2; i += 256) hist[i] = 0;
    __syncthreads();

    // pass A: histogram endpoint buckets
    for (int i = tid; i < EPB; i += 256) {
        int e = e0 + i;
        if (e < NE) {
            int s = edge_index[e];
            int d = edge_index[NE + e];
            atomicAdd(&hist[s >> CHUNK2_LOG], 1);
            atomicAdd(&hist[d >> CHUNK2_LOG], 1);
        }
    }
    __syncthreads();

    // Hillis-Steele inclusive scan over SCANW (non-divergent syncs)
    for (int i = tid; i < SCANW; i += 256)
        scanbuf[i] = (i < NCHUNK2) ? hist[i] : 0;
    __syncthreads();
    for (int off = 1; off < SCANW; off <<= 1) {
        int v[SCANW / 256];
#pragma unroll
        for (int j = 0; j < SCANW / 256; ++j) {
            int i = tid + j * 256;
            v[j] = (i >= off) ? scanbuf[i - off] : 0;
        }
        __syncthreads();
#pragma unroll
        for (int j = 0; j < SCANW / 256; ++j) {
            int i = tid + j * 256;
            if (i >= off) scanbuf[i] += v[j];
        }
        __syncthreads();
    }
    for (int i = tid; i < NCHUNK2; i += 256) {
        int lb = scanbuf[i] - hist[i];
        lbase[i] = lb;
        lcur[i]  = lb;
        gbase[i] = atomicAdd(&g_cursor2[i], hist[i]);
    }
    __syncthreads();

    // pass B: stage 2 records per edge into bucket-grouped LDS
    for (int i = tid; i < EPB; i += 256) {
        int e = e0 + i;
        if (e >= NE) continue;
        int s = edge_index[e];
        int d = edge_index[NE + e];
        unsigned cb = __float_as_uint(edge_attr[2 * (size_t)e]);

        int ks = s >> CHUNK2_LOG;
        int sl = atomicAdd(&lcur[ks], 1);
        u32x2 rs; rs.x = ((unsigned)(s & (CHUNK2 - 1)) << 17) | (unsigned)d; rs.y = cb;
        s_rec[sl] = rs;
        int kd = d >> CHUNK2_LOG;
        sl = atomicAdd(&lcur[kd], 1);
        u32x2 rd; rd.x = ((unsigned)(d & (CHUNK2 - 1)) << 17) | (unsigned)s; rd.y = cb;
        s_rec[sl] = rd;
    }
    __syncthreads();

    // flush: wave w handles buckets w, w+4, ... — contiguous CACHED runs
    int wave = tid >> 6, lane = tid & 63;
    for (int k = wave; k < NCHUNK2; k += 4) {
        int cnt = hist[k];
        if (cnt == 0) continue;
        int lb = lbase[k], gb = gbase[k];
        u32x2* dst = &g_rec2[(size_t)k * CAP2];
        for (int i = lane; i < cnt; i += 64) {
            if (gb + i < CAP2)
                dst[gb + i] = s_rec[lb + i];
        }
    }
}

// ---------------------------------------------------------------------------
// Sort-gather: per 128-node chunk, 512 threads (16 waves/CU at 2 blocks/CU):
// LDS-atomic count -> scan -> LDS-atomic place into s_rec runs -> register
// accumulation by 4-lane node owners. Record reads cached (L3-hot).
// ---------------------------------------------------------------------------
__global__ __launch_bounds__(512) void sortgather_kernel(
    const float* __restrict__ demands)
{
    __shared__ u32x2 s_rec[CAP2];       // 72 KB sorted (other, c) runs
    __shared__ int   hist[CHUNK2];
    __shared__ int   hbase[CHUNK2];
    __shared__ int   hcur[CHUNK2];
    __shared__ int   scanbuf[CHUNK2];
    __shared__ float wred[8];

    int tid  = threadIdx.x;
    int wave = tid >> 6, lane = tid & 63;
    int c = blockIdx.x;
    int cnt = g_cursor2[c];
    if (cnt > CAP2) cnt = CAP2;
    const u32x2* rec = &g_rec2[(size_t)c * CAP2];

    if (tid < CHUNK2) hist[tid] = 0;
    __syncthreads();

    // count pass
    for (int i = tid; i < cnt; i += 512)
        atomicAdd(&hist[rec[i].x >> 17], 1);
    __syncthreads();

    // exclusive scan over 128 (non-divergent syncs)
    if (tid < CHUNK2) scanbuf[tid] = hist[tid];
    __syncthreads();
    for (int off = 1; off < CHUNK2; off <<= 1) {
        int v = (tid < CHUNK2 && tid >= off) ? scanbuf[tid - off] : 0;
        __syncthreads();
        if (tid < CHUNK2 && tid >= off) scanbuf[tid] += v;
        __syncthreads();
    }
    if (tid < CHUNK2) {
        int lb = scanbuf[tid] - hist[tid];
        hbase[tid] = lb;
        hcur[tid]  = lb;
    }
    __syncthreads();

    // place pass
    for (int i = tid; i < cnt; i += 512) {
        u32x2 r = rec[i];
        int sl = atomicAdd(&hcur[r.x >> 17], 1);
        s_rec[sl] = r;
    }
    __syncthreads();

    // owner accumulate: 4 lanes per node, registers only, 2x unroll
    float contrib = 0.0f;
    {
        int nl = tid >> 2, p = tid & 3;
        int n = (c << CHUNK2_LOG) + nl;
        int off0 = hbase[nl];
        int cn = hist[nl];
        int nc = (n < N) ? n : 0;
        const f32x4* hm = (const f32x4*)&g_heads_t[nc << 3];
        f32x4 m0 = hm[0], m1 = hm[1];
        f32x4 a0 = {0.f, 0.f, 0.f, 0.f};
        f32x4 a1 = {0.f, 0.f, 0.f, 0.f};
        int i = p;
        for (; i + 4 < cn; i += 8) {
            u32x2 r0 = s_rec[off0 + i];
            u32x2 r1 = s_rec[off0 + i + 4];
            float c0 = __uint_as_float(r0.y);
            float c1 = __uint_as_float(r1.y);
            const f32x4* ho0 = (const f32x4*)&g_heads_t[(r0.x & 0x1FFFFu) << 3];
            const f32x4* ho1 = (const f32x4*)&g_heads_t[(r1.x & 0x1FFFFu) << 3];
            f32x4 o00 = ho0[0], o01 = ho0[1];
            f32x4 o10 = ho1[0], o11 = ho1[1];
            a0 += c0 * (m0 - o00);
            a1 += c0 * (m1 - o01);
            a0 += c1 * (m0 - o10);
            a1 += c1 * (m1 - o11);
        }
        for (; i < cn; i += 4) {
            u32x2 r0 = s_rec[off0 + i];
            float c0 = __uint_as_float(r0.y);
            const f32x4* ho0 = (const f32x4*)&g_heads_t[(r0.x & 0x1FFFFu) << 3];
            f32x4 o00 = ho0[0], o01 = ho0[1];
            a0 += c0 * (m0 - o00);
            a1 += c0 * (m1 - o01);
        }
        float acc[8] = {a0.x, a0.y, a0.z, a0.w, a1.x, a1.y, a1.z, a1.w};
        bool emit = (p == 0) && (n < N);
#pragma unroll
        for (int j = 0; j < 8; ++j) {
            float v = acc[j];
            v += __shfl_xor(v, 1, 64);
            v += __shfl_xor(v, 2, 64);
            if (emit) {
                float vv = v - demands[j * N + n];
                contrib = fmaf(vv, vv, contrib);
            }
        }
    }

    // block reduction of continuity partial
    for (int off = 32; off > 0; off >>= 1)
        contrib += __shfl_down(contrib, off, 64);
    if (lane == 0) wred[wave] = contrib;
    __syncthreads();
    if (tid == 0) {
        float bsum = 0.0f;
#pragma unroll
        for (int w = 0; w < 8; ++w) bsum += wred[w];
        unsafeAtomicAdd(&g_accum, bsum);
    }
}

// ---------------------------------------------------------------------------
// Boundary loss + finalize scalars.
// ---------------------------------------------------------------------------
__global__ __launch_bounds__(512) void finalize_kernel(
    const float* __restrict__ node_heads,
    const int* __restrict__ res_nodes,      // (64,) int32
    const float* __restrict__ res_head,     // (1,)
    float* __restrict__ out)
{
    __shared__ float ssum[8];
    int t = threadIdx.x;          // 512 = B*64
    int b = t >> 6;
    int j = t & 63;
    float pred = node_heads[b * N + res_nodes[j]];
    float diff = pred - res_head[0];
    float local = diff * diff;
    for (int off = 32; off > 0; off >>= 1)
        local += __shfl_down(local, off, 64);
    if ((t & 63) == 0) ssum[t >> 6] = local;
    __syncthreads();
    if (t == 0) {
        float bsum = 0.0f;
        for (int w = 0; w < 8; ++w) bsum += ssum[w];
        float boundary = bsum / 512.0f;
        float continuity = g_accum / (float)(B * N);
        out[0] = continuity;
        out[1] = boundary;
        out[2] = continuity + boundary;     // LAMBDA_PHYSICS = 1.0
    }
}

extern "C" void kernel_launch(void* const* d_in, const int* in_sizes, int n_in,
                              void* d_out, int out_size, void* d_ws, size_t ws_size,
                              hipStream_t stream) {
    const float* node_heads = (const float*)d_in[0];
    const float* demands    = (const float*)d_in[1];
    const int*   edge_index = (const int*)d_in[2];    // int32 per harness
    const float* edge_attr  = (const float*)d_in[3];
    const int*   res_nodes  = (const int*)d_in[4];    // int32 per harness
    const float* res_head   = (const float*)d_in[5];

    float* out = (float*)d_out;   // [cont, bound, total, flows(B,E)]

    zero_kernel<<<1, 256, 0, stream>>>();
    transpose_kernel<<<(N * B + 255) / 256, 256, 0, stream>>>(node_heads);
    flows_kernel<<<(NE + 255) / 256, 256, 0, stream>>>(
        edge_index, edge_attr, out + 3);
    records_kernel<<<(NE + EPB - 1) / EPB, 256, 0, stream>>>(
        edge_index, edge_attr);
    sortgather_kernel<<<NCHUNK2, 512, 0, stream>>>(demands);
    finalize_kernel<<<1, 512, 0, stream>>>(node_heads, res_nodes, res_head, out);
}

// Round 10
// 404.574 us; speedup vs baseline: 1.3609x; 1.3609x over previous
//
#include <hip/hip_runtime.h>

#define B 8
#define N 100000
#define NE 3200000
#define CHUNK2_LOG 8
#define CHUNK2 256            // nodes per record bucket (r10: 128->256)
#define NCHUNK2 391           // ceil(N / 256)
#define CAP2 18432            // per-bucket record capacity (mean 16384, +16 sigma)
#define EPB 2048              // phase-1 edges per block
#define RPB (2 * EPB)         // records staged per block = 4096
#define SCANW 512             // scan width (pow2 >= NCHUNK2)

typedef float f32x4 __attribute__((ext_vector_type(4)));
typedef unsigned u32x2 __attribute__((ext_vector_type(2)));

// Thin 8-B records: key = (me_local<<17)|other (8b local + 17b other), val =
// conductance bits. Contribution to node me is ALWAYS +c*(h[me]-h[other]).
// ROUND-10: r8 structure (best, 480us) with per-block FIXED costs halved —
// r9's split isolated them at ~98us/kernel (scan width, serial flush buckets,
// global cursor atomics all scale with bucket count). 256-node buckets halve
// all three; flush runs lengthen 5.2->10.5 (denser stores); scanbuf aliases
// s_rec -> 39KB LDS -> 4 blocks/CU. Sortgather takes 256-node chunks with
// 512 thr + 144KB LDS (1 block/CU, 8 waves — same as r8's 2x4).
__device__ u32x2 g_rec2[(size_t)NCHUNK2 * CAP2];                 // 57.7 MB
__device__ int   g_cursor2[NCHUNK2];
__device__ float g_heads_t[N * B];                               // node-major heads
__device__ float g_accum;

// ---------------------------------------------------------------------------
__global__ __launch_bounds__(256) void zero_kernel() {
    for (int i = threadIdx.x; i < NCHUNK2; i += 256) g_cursor2[i] = 0;
    if (threadIdx.x == 0) g_accum = 0.0f;
}

// heads (B,N) -> heads_t (N,B): each node's 8 batch values contiguous (32 B).
__global__ __launch_bounds__(256) void transpose_kernel(
    const float* __restrict__ node_heads)
{
    int i = blockIdx.x * blockDim.x + threadIdx.x;   // i = n*8 + b
    if (i >= N * B) return;
    int n = i >> 3, b = i & 7;
    g_heads_t[i] = node_heads[b * N + n];            // stays L2/L3-hot for gathers
}

// ---------------------------------------------------------------------------
// Phase 1 (fused, r8-proven): flows + records binned by 256-node chunk.
// LDS hist -> scan -> LDS-staged placement -> coalesced cached flush.
// ---------------------------------------------------------------------------
__global__ __launch_bounds__(256) void phase1_kernel(
    const int* __restrict__ edge_index,     // (2, E) int32
    const float* __restrict__ edge_attr,    // (E, 2)
    float* __restrict__ flows_out)          // (B, E)
{
    __shared__ int   hist[NCHUNK2];
    __shared__ int   lbase[NCHUNK2];
    __shared__ int   gbase[NCHUNK2];
    __shared__ int   lcur[NCHUNK2];
    __shared__ u32x2 s_rec[RPB];        // 32 KB staging; scanbuf aliases head
    int* scanbuf = (int*)s_rec;         // consumed before pass B writes s_rec

    int tid = threadIdx.x;
    int e0 = blockIdx.x * EPB;

    for (int i = tid; i < NCHUNK2; i += 256) hist[i] = 0;
    __syncthreads();

    // pass A: histogram endpoint buckets
    for (int i = tid; i < EPB; i += 256) {
        int e = e0 + i;
        if (e < NE) {
            int s = edge_index[e];
            int d = edge_index[NE + e];
            atomicAdd(&hist[s >> CHUNK2_LOG], 1);
            atomicAdd(&hist[d >> CHUNK2_LOG], 1);
        }
    }
    __syncthreads();

    // Hillis-Steele inclusive scan over SCANW (non-divergent syncs)
    for (int i = tid; i < SCANW; i += 256)
        scanbuf[i] = (i < NCHUNK2) ? hist[i] : 0;
    __syncthreads();
    for (int off = 1; off < SCANW; off <<= 1) {
        int v[SCANW / 256];
#pragma unroll
        for (int j = 0; j < SCANW / 256; ++j) {
            int i = tid + j * 256;
            v[j] = (i >= off) ? scanbuf[i - off] : 0;
        }
        __syncthreads();
#pragma unroll
        for (int j = 0; j < SCANW / 256; ++j) {
            int i = tid + j * 256;
            if (i >= off) scanbuf[i] += v[j];
        }
        __syncthreads();
    }
    for (int i = tid; i < NCHUNK2; i += 256) {
        int lb = scanbuf[i] - hist[i];
        lbase[i] = lb;
        lcur[i]  = lb;
        gbase[i] = atomicAdd(&g_cursor2[i], hist[i]);
    }
    __syncthreads();                    // scanbuf dead past here

    // pass B: flows + stage 2 records per edge into bucket-grouped LDS
    for (int i = tid; i < EPB; i += 256) {
        int e = e0 + i;
        if (e >= NE) continue;
        int s = edge_index[e];
        int d = edge_index[NE + e];
        float c = edge_attr[2 * (size_t)e];

        const f32x4* hs4 = (const f32x4*)&g_heads_t[s << 3];
        const f32x4* hd4 = (const f32x4*)&g_heads_t[d << 3];
        f32x4 a0 = hs4[0], a1 = hs4[1];
        f32x4 b0 = hd4[0], b1 = hd4[1];
        f32x4 f0 = c * (a0 - b0);
        f32x4 f1 = c * (a1 - b1);

        __builtin_nontemporal_store(f0.x, &flows_out[0 * NE + e]);
        __builtin_nontemporal_store(f0.y, &flows_out[1 * NE + e]);
        __builtin_nontemporal_store(f0.z, &flows_out[2 * NE + e]);
        __builtin_nontemporal_store(f0.w, &flows_out[3 * NE + e]);
        __builtin_nontemporal_store(f1.x, &flows_out[4 * NE + e]);
        __builtin_nontemporal_store(f1.y, &flows_out[5 * NE + e]);
        __builtin_nontemporal_store(f1.z, &flows_out[6 * NE + e]);
        __builtin_nontemporal_store(f1.w, &flows_out[7 * NE + e]);

        unsigned cb = __float_as_uint(c);
        int ks = s >> CHUNK2_LOG;
        int sl = atomicAdd(&lcur[ks], 1);
        u32x2 rs; rs.x = ((unsigned)(s & (CHUNK2 - 1)) << 17) | (unsigned)d; rs.y = cb;
        s_rec[sl] = rs;
        int kd = d >> CHUNK2_LOG;
        sl = atomicAdd(&lcur[kd], 1);
        u32x2 rd; rd.x = ((unsigned)(d & (CHUNK2 - 1)) << 17) | (unsigned)s; rd.y = cb;
        s_rec[sl] = rd;
    }
    __syncthreads();

    // flush: wave w handles buckets w, w+4, ... — contiguous CACHED runs
    // (391 buckets, avg 10.5 recs/run: half the serial iterations of r8,
    //  denser lines; L3 merges run boundaries across blocks)
    int wave = tid >> 6, lane = tid & 63;
    for (int k = wave; k < NCHUNK2; k += 4) {
        int cnt = hist[k];
        if (cnt == 0) continue;
        int lb = lbase[k], gb = gbase[k];
        u32x2* dst = &g_rec2[(size_t)k * CAP2];
        for (int i = lane; i < cnt; i += 64) {
            if (gb + i < CAP2)
                dst[gb + i] = s_rec[lb + i];
        }
    }
}

// ---------------------------------------------------------------------------
// Sort-gather: per 256-node chunk, 512 threads, 144 KB LDS (1 block/CU,
// 8 waves — gfx950 allows up to 160 KB/workgroup): LDS-atomic count -> scan
// -> LDS-atomic place into s_rec runs -> register accumulation by 2-lane
// node owners. Record reads cached (L3-hot after phase1).
// ---------------------------------------------------------------------------
__global__ __launch_bounds__(512) void sortgather_kernel(
    const float* __restrict__ demands)
{
    __shared__ u32x2 s_rec[CAP2];       // 144 KB sorted (other, c) runs
    __shared__ int   hist[CHUNK2];
    __shared__ int   hbase[CHUNK2];
    __shared__ int   hcur[CHUNK2];
    __shared__ int   scanbuf[CHUNK2];
    __shared__ float wred[8];

    int tid  = threadIdx.x;
    int wave = tid >> 6, lane = tid & 63;
    int c = blockIdx.x;
    int cnt = g_cursor2[c];
    if (cnt > CAP2) cnt = CAP2;
    const u32x2* rec = &g_rec2[(size_t)c * CAP2];

    if (tid < CHUNK2) hist[tid] = 0;
    __syncthreads();

    // count pass
    for (int i = tid; i < cnt; i += 512)
        atomicAdd(&hist[rec[i].x >> 17], 1);
    __syncthreads();

    // exclusive scan over 256 (non-divergent syncs)
    if (tid < CHUNK2) scanbuf[tid] = hist[tid];
    __syncthreads();
    for (int off = 1; off < CHUNK2; off <<= 1) {
        int v = (tid < CHUNK2 && tid >= off) ? scanbuf[tid - off] : 0;
        __syncthreads();
        if (tid < CHUNK2 && tid >= off) scanbuf[tid] += v;
        __syncthreads();
    }
    if (tid < CHUNK2) {
        int lb = scanbuf[tid] - hist[tid];
        hbase[tid] = lb;
        hcur[tid]  = lb;
    }
    __syncthreads();

    // place pass
    for (int i = tid; i < cnt; i += 512) {
        u32x2 r = rec[i];
        int sl = atomicAdd(&hcur[r.x >> 17], 1);
        s_rec[sl] = r;
    }
    __syncthreads();

    // owner accumulate: 2 lanes per node, registers only, 2x unroll
    float contrib = 0.0f;
    {
        int nl = tid >> 1, p = tid & 1;
        int n = (c << CHUNK2_LOG) + nl;
        int off0 = hbase[nl];
        int cn = hist[nl];
        int nc = (n < N) ? n : 0;
        const f32x4* hm = (const f32x4*)&g_heads_t[nc << 3];
        f32x4 m0 = hm[0], m1 = hm[1];
        f32x4 a0 = {0.f, 0.f, 0.f, 0.f};
        f32x4 a1 = {0.f, 0.f, 0.f, 0.f};
        int i = p;
        for (; i + 2 < cn; i += 4) {
            u32x2 r0 = s_rec[off0 + i];
            u32x2 r1 = s_rec[off0 + i + 2];
            float c0 = __uint_as_float(r0.y);
            float c1 = __uint_as_float(r1.y);
            const f32x4* ho0 = (const f32x4*)&g_heads_t[(r0.x & 0x1FFFFu) << 3];
            const f32x4* ho1 = (const f32x4*)&g_heads_t[(r1.x & 0x1FFFFu) << 3];
            f32x4 o00 = ho0[0], o01 = ho0[1];
            f32x4 o10 = ho1[0], o11 = ho1[1];
            a0 += c0 * (m0 - o00);
            a1 += c0 * (m1 - o01);
            a0 += c1 * (m0 - o10);
            a1 += c1 * (m1 - o11);
        }
        for (; i < cn; i += 2) {
            u32x2 r0 = s_rec[off0 + i];
            float c0 = __uint_as_float(r0.y);
            const f32x4* ho0 = (const f32x4*)&g_heads_t[(r0.x & 0x1FFFFu) << 3];
            f32x4 o00 = ho0[0], o01 = ho0[1];
            a0 += c0 * (m0 - o00);
            a1 += c0 * (m1 - o01);
        }
        float acc[8] = {a0.x, a0.y, a0.z, a0.w, a1.x, a1.y, a1.z, a1.w};
        bool emit = (p == 0) && (n < N);
#pragma unroll
        for (int j = 0; j < 8; ++j) {
            float v = acc[j];
            v += __shfl_xor(v, 1, 64);
            if (emit) {
                float vv = v - demands[j * N + n];
                contrib = fmaf(vv, vv, contrib);
            }
        }
    }

    // block reduction of continuity partial
    for (int off = 32; off > 0; off >>= 1)
        contrib += __shfl_down(contrib, off, 64);
    if (lane == 0) wred[wave] = contrib;
    __syncthreads();
    if (tid == 0) {
        float bsum = 0.0f;
#pragma unroll
        for (int w = 0; w < 8; ++w) bsum += wred[w];
        unsafeAtomicAdd(&g_accum, bsum);
    }
}

// ---------------------------------------------------------------------------
// Boundary loss + finalize scalars.
// ---------------------------------------------------------------------------
__global__ __launch_bounds__(512) void finalize_kernel(
    const float* __restrict__ node_heads,
    const int* __restrict__ res_nodes,      // (64,) int32
    const float* __restrict__ res_head,     // (1,)
    float* __restrict__ out)
{
    __shared__ float ssum[8];
    int t = threadIdx.x;          // 512 = B*64
    int b = t >> 6;
    int j = t & 63;
    float pred = node_heads[b * N + res_nodes[j]];
    float diff = pred - res_head[0];
    float local = diff * diff;
    for (int off = 32; off > 0; off >>= 1)
        local += __shfl_down(local, off, 64);
    if ((t & 63) == 0) ssum[t >> 6] = local;
    __syncthreads();
    if (t == 0) {
        float bsum = 0.0f;
        for (int w = 0; w < 8; ++w) bsum += ssum[w];
        float boundary = bsum / 512.0f;
        float continuity = g_accum / (float)(B * N);
        out[0] = continuity;
        out[1] = boundary;
        out[2] = continuity + boundary;     // LAMBDA_PHYSICS = 1.0
    }
}

extern "C" void kernel_launch(void* const* d_in, const int* in_sizes, int n_in,
                              void* d_out, int out_size, void* d_ws, size_t ws_size,
                              hipStream_t stream) {
    const float* node_heads = (const float*)d_in[0];
    const float* demands    = (const float*)d_in[1];
    const int*   edge_index = (const int*)d_in[2];    // int32 per harness
    const float* edge_attr  = (const float*)d_in[3];
    const int*   res_nodes  = (const int*)d_in[4];    // int32 per harness
    const float* res_head   = (const float*)d_in[5];

    float* out = (float*)d_out;   // [cont, bound, total, flows(B,E)]

    zero_kernel<<<1, 256, 0, stream>>>();
    transpose_kernel<<<(N * B + 255) / 256, 256, 0, stream>>>(node_heads);
    phase1_kernel<<<(NE + EPB - 1) / EPB, 256, 0, stream>>>(
        edge_index, edge_attr, out + 3);
    sortgather_kernel<<<NCHUNK2, 512, 0, stream>>>(demands);
    finalize_kernel<<<1, 512, 0, stream>>>(node_heads, res_nodes, res_head, out);
}